// Round 3
// baseline (135.260 us; speedup 1.0000x reference)
//
#include <hip/hip_runtime.h>
#include <stdint.h>

#define N_ATOMS 2048
#define KNN     12
#define CAP     128
#define QCAP    2048                 // per-chunk queue bound: 256 lanes * 8 combos max
#define NEDGE   (N_ATOMS * KNN)
#define OFF_EDGE 0
#define OFF_DIST (3 * NEDGE)
#define OFF_SRC  (OFF_DIST + NEDGE)
#define OFF_DST  (OFF_SRC + NEDGE)
#define OFF_NUM  (OFF_DST + NEDGE)
#define DELTA   5e-4f                // cheap-vs-exact frac guard band (err bound ~2e-6)

// Single fused kernel: one block per center atom. Each block independently
// classifies which of the 27*2048 periodic replicas are valid (cheap frac test
// on the unshifted atom + exact reference-chain test inside the DELTA band),
// queues valid (i,j) pairs in LDS, computes reference-identical d2 chains,
// threshold-filters, and extracts the exact top-12 via 64-lane shfl-min rounds
// on packed (d2_bits<<32 | j*2048+i) keys (== lax.top_k tie-break).
__global__ __launch_bounds__(256) void knn_fused(
    const float* __restrict__ pos, const float* __restrict__ cell,
    const int* __restrict__ numbers, float* __restrict__ out)
{
    __shared__ float sh_shift[27][3];
    __shared__ unsigned sh_q[QCAP];
    __shared__ unsigned long long sh_keys[CAP];
    __shared__ int sh_qn;
    __shared__ int sh_cnt;

    const int a = blockIdx.x;
    const int tid = threadIdx.x;

    float c[9];
#pragma unroll
    for (int q = 0; q < 9; ++q) c[q] = cell[q];

    // inverse via double adjugate, rounded to f32 (identical to passing rounds)
    double a00 = c[0], a01 = c[1], a02 = c[2];
    double a10 = c[3], a11 = c[4], a12 = c[5];
    double a20 = c[6], a21 = c[7], a22 = c[8];
    double det = a00 * (a11 * a22 - a12 * a21)
               - a01 * (a10 * a22 - a12 * a20)
               + a02 * (a10 * a21 - a11 * a20);
    double id = 1.0 / det;
    float M[9];  // M[r*3+d]; frac_d = fma(pz,M[6+d], fma(py,M[3+d], px*M[d]))
    M[0] = (float)(( a11 * a22 - a12 * a21) * id);
    M[1] = (float)((-(a01 * a22 - a02 * a21)) * id);
    M[2] = (float)(( a01 * a12 - a02 * a11) * id);
    M[3] = (float)((-(a10 * a22 - a12 * a20)) * id);
    M[4] = (float)(( a00 * a22 - a02 * a20) * id);
    M[5] = (float)((-(a00 * a12 - a02 * a10)) * id);
    M[6] = (float)(( a10 * a21 - a11 * a20) * id);
    M[7] = (float)((-(a00 * a21 - a01 * a20)) * id);
    M[8] = (float)(( a00 * a11 - a01 * a10) * id);

    float rn0 = sqrtf(c[0]*c[0] + c[1]*c[1] + c[2]*c[2]);
    float rn1 = sqrtf(c[3]*c[3] + c[4]*c[4] + c[5]*c[5]);
    float rn2 = sqrtf(c[6]*c[6] + c[7]*c[7] + c[8]*c[8]);
    float dxm = 0.1f * fminf(rn0, fminf(rn1, rn2));
    const float e0 = dxm / rn0, e1 = dxm / rn1, e2 = dxm / rn2;

    float vol = (float)fabs(det);
    float T = powf(3.0f * 48.0f * vol / (4.0f * 3.14159265f * (float)N_ATOMS), 2.0f / 3.0f);

    if (tid < 27) {
        int j = tid;
        float o0 = (float)(j / 9 - 1);
        float o1 = (float)((j / 3) % 3 - 1);
        float o2 = (float)(j % 3 - 1);
        sh_shift[j][0] = __fadd_rn(__fadd_rn(__fmul_rn(o0, c[0]), __fmul_rn(o1, c[3])), __fmul_rn(o2, c[6]));
        sh_shift[j][1] = __fadd_rn(__fadd_rn(__fmul_rn(o0, c[1]), __fmul_rn(o1, c[4])), __fmul_rn(o2, c[7]));
        sh_shift[j][2] = __fadd_rn(__fadd_rn(__fmul_rn(o0, c[2]), __fmul_rn(o1, c[5])), __fmul_rn(o2, c[8]));
    }

    if (a < N_ATOMS / 256) {
        int mm = a * 256 + tid;
        out[OFF_NUM + mm] = (float)numbers[mm];
    }

    const float cx = pos[a * 3 + 0];
    const float cy = pos[a * 3 + 1];
    const float cz = pos[a * 3 + 2];
    const float cc = __fadd_rn(__fadd_rn(__fmul_rn(cx, cx), __fmul_rn(cy, cy)), __fmul_rn(cz, cz));

    int cnt = 0;
    for (int att = 0; att < 8; ++att) {
        if (tid == 0) sh_cnt = 0;
        for (int ch = 0; ch < N_ATOMS / 256; ++ch) {
            __syncthreads();                 // prev drain done / sh_cnt reset visible
            if (tid == 0) sh_qn = 0;
            __syncthreads();

            // ---- classify one atom per lane, push valid (i,j) combos ----
            {
                int i = ch * 256 + tid;
                float pxi = pos[i * 3 + 0], pyi = pos[i * 3 + 1], pzi = pos[i * 3 + 2];
                float fr0 = __fmaf_rn(pzi, M[6], __fmaf_rn(pyi, M[3], __fmul_rn(pxi, M[0])));
                float fr1 = __fmaf_rn(pzi, M[7], __fmaf_rn(pyi, M[4], __fmul_rn(pxi, M[1])));
                float fr2 = __fmaf_rn(pzi, M[8], __fmaf_rn(pyi, M[5], __fmul_rn(pxi, M[2])));
                // per dim: o=0 always valid; alt = +1 (k=2) iff fr<=e, alt = -1 (k=0) iff fr>=1-e
                int alt0 = 1, has0 = 0, unc0 = 0;
                if (fr0 <= e0 + DELTA)              { alt0 = 2; has0 = 1; unc0 = (fr0 > e0 - DELTA); }
                else if (fr0 >= 1.0f - e0 - DELTA)  { alt0 = 0; has0 = 1; unc0 = (fr0 < 1.0f - e0 + DELTA); }
                int alt1 = 1, has1 = 0, unc1 = 0;
                if (fr1 <= e1 + DELTA)              { alt1 = 2; has1 = 1; unc1 = (fr1 > e1 - DELTA); }
                else if (fr1 >= 1.0f - e1 - DELTA)  { alt1 = 0; has1 = 1; unc1 = (fr1 < 1.0f - e1 + DELTA); }
                int alt2 = 1, has2 = 0, unc2 = 0;
                if (fr2 <= e2 + DELTA)              { alt2 = 2; has2 = 1; unc2 = (fr2 > e2 - DELTA); }
                else if (fr2 >= 1.0f - e2 - DELTA)  { alt2 = 0; has2 = 1; unc2 = (fr2 < 1.0f - e2 + DELTA); }

                int ncomb = (1 + has0) * (1 + has1) * (1 + has2);
                int base = atomicAdd(&sh_qn, ncomb);
#pragma unroll
                for (int s = 0; s < 8; ++s) {
                    int s0 = s & 1, s1 = (s >> 1) & 1, s2 = (s >> 2) & 1;
                    if ((s0 & (has0 ^ 1)) | (s1 & (has1 ^ 1)) | (s2 & (has2 ^ 1))) continue;
                    int k0 = s0 ? alt0 : 1;
                    int k1 = s1 ? alt1 : 1;
                    int k2 = s2 ? alt2 : 1;
                    int j = k0 * 9 + k1 * 3 + k2;
                    int u = (s0 & unc0) | (s1 & unc1) | (s2 & unc2);
                    sh_q[base++] = (unsigned)(i | (j << 11) | (u << 16));
                }
            }
            __syncthreads();

            // ---- drain queue uniformly ----
            int qn = sh_qn;
            for (int q = tid; q < qn; q += 256) {
                unsigned e = sh_q[q];
                int i = (int)(e & 2047u);
                int j = (int)((e >> 11) & 31u);
                if (i == a && j == 13) continue;   // self
                float px = __fadd_rn(pos[i * 3 + 0], sh_shift[j][0]);
                float py = __fadd_rn(pos[i * 3 + 1], sh_shift[j][1]);
                float pz = __fadd_rn(pos[i * 3 + 2], sh_shift[j][2]);
                if (e >> 16) {  // boundary band: exact reference validity
                    float f0 = __fmaf_rn(pz, M[6], __fmaf_rn(py, M[3], __fmul_rn(px, M[0])));
                    float f1 = __fmaf_rn(pz, M[7], __fmaf_rn(py, M[4], __fmul_rn(px, M[1])));
                    float f2 = __fmaf_rn(pz, M[8], __fmaf_rn(py, M[5], __fmul_rn(px, M[2])));
                    bool v = (f0 >= -e0) && (f0 <= 1.0f + e0)
                          && (f1 >= -e1) && (f1 <= 1.0f + e1)
                          && (f2 >= -e2) && (f2 <= 1.0f + e2);
                    if (!v) continue;
                }
                float pp  = __fadd_rn(__fadd_rn(__fmul_rn(px, px), __fmul_rn(py, py)), __fmul_rn(pz, pz));
                float dot = __fmaf_rn(cz, pz, __fmaf_rn(cy, py, __fmul_rn(cx, px)));
                float d2  = __fsub_rn(__fadd_rn(cc, pp), __fmul_rn(2.0f, dot));
                if (d2 < T) {
                    int slot = atomicAdd(&sh_cnt, 1);
                    if (slot < CAP)
                        sh_keys[slot] = ((unsigned long long)__float_as_uint(d2) << 32)
                                      | (unsigned)(j * N_ATOMS + i);
                }
            }
        }
        __syncthreads();
        cnt = sh_cnt;
        __syncthreads();
        if (cnt >= KNN && cnt <= CAP) break;
        T = (cnt < KNN) ? T * 2.0f : T * 0.5f;
    }

    // ---- exact top-12 extraction (wave 0) ----
    if (tid < 64) {
        const unsigned long long MAXK = ~0ull;
        unsigned long long k0 = (tid < cnt) ? sh_keys[tid] : MAXK;
        unsigned long long k1 = (tid + 64 < cnt) ? sh_keys[tid + 64] : MAXK;
        unsigned long long lo = (k0 < k1) ? k0 : k1;
        unsigned long long hi = (k0 < k1) ? k1 : k0;
#pragma unroll
        for (int r = 0; r < KNN; ++r) {
            unsigned long long mn = lo;
#pragma unroll
            for (int off = 32; off; off >>= 1) {
                unsigned long long o = __shfl_xor(mn, off, 64);
                mn = (o < mn) ? o : mn;
            }
            if (lo == mn) { lo = hi; hi = MAXK; }  // consume winner
            if (tid == r) {
                unsigned mval = (unsigned)(mn & 0xffffffffu);
                float d2 = __uint_as_float((unsigned)(mn >> 32));
                int ii = (int)(mval & 2047u);
                int jj = (int)(mval >> 11);
                float px = __fadd_rn(pos[ii * 3 + 0], sh_shift[jj][0]);
                float py = __fadd_rn(pos[ii * 3 + 1], sh_shift[jj][1]);
                float pz = __fadd_rn(pos[ii * 3 + 2], sh_shift[jj][2]);
                int eo = a * KNN + r;
                out[OFF_EDGE + 3 * eo + 0] = __fsub_rn(px, cx);
                out[OFF_EDGE + 3 * eo + 1] = __fsub_rn(py, cy);
                out[OFF_EDGE + 3 * eo + 2] = __fsub_rn(pz, cz);
                out[OFF_DIST + eo] = sqrtf(fmaxf(d2, 0.0f));
                out[OFF_SRC + eo]  = (float)ii;
                out[OFF_DST + eo]  = (float)a;
            }
        }
    }
}

extern "C" void kernel_launch(void* const* d_in, const int* in_sizes, int n_in,
                              void* d_out, int out_size, void* d_ws, size_t ws_size,
                              hipStream_t stream) {
    const float* pos     = (const float*)d_in[0];
    const float* cell    = (const float*)d_in[1];
    const int*   numbers = (const int*)d_in[2];
    float*       out     = (float*)d_out;
    (void)d_ws; (void)ws_size;

    hipLaunchKernelGGL(knn_fused, dim3(N_ATOMS), dim3(256), 0, stream,
                       pos, cell, numbers, out);
}